// Round 1
// baseline (158.568 us; speedup 1.0000x reference)
//
#include <hip/hip_runtime.h>
#include <hip/hip_bf16.h>
#include <float.h>

// B=4096, D=512, N=8192, temp=0.5
#define BN_ 4096
#define DD  512
#define NN  8192
#define SCALE 2.0f   // 1/temperature
#define BUF 16384    // elements per LDS K-tile buffer (256 rows x 64 K)

typedef unsigned short u16;
typedef __attribute__((ext_vector_type(8))) short short8;   // 8 bf16 = 4 VGPRs
typedef __attribute__((ext_vector_type(4))) float floatx4;  // MFMA acc

struct alignas(8) U16x4 { u16 x, y, z, w; };

__device__ __forceinline__ u16 f2bf(float f) {
    union { float f; unsigned u; } c; c.f = f;
    unsigned u = c.u;
    unsigned r = (u + 0x7fffu + ((u >> 16) & 1u)) >> 16;   // RNE
    return (u16)r;
}

__device__ __forceinline__ void async_copy16(const u16* g, u16* l) {
    __builtin_amdgcn_global_load_lds(
        (const __attribute__((address_space(1))) void*)g,
        (__attribute__((address_space(3))) void*)l, 16, 0, 0);
}

// ------ kernel 1: fp32 -> bf16 concat + per-block positive-dot partial ------
// (unchanged; block 0 zero-inits d_out, harness poisons it with 0xAA)
__global__ __launch_bounds__(256) void convert_pos_kernel(const float* __restrict__ hi,
                                                          const float* __restrict__ hj,
                                                          u16* __restrict__ H,
                                                          float* __restrict__ Pos,
                                                          float* __restrict__ out) {
    __shared__ float red[4];
    int t = blockIdx.x * 256 + threadIdx.x;     // 2048 blocks -> 524288 threads
    int e = t * 4;
    const int BD = BN_ * DD;
    float4 a = *(const float4*)(hi + e);
    float4 b = *(const float4*)(hj + e);
    U16x4 oa, ob;
    oa.x = f2bf(a.x); oa.y = f2bf(a.y); oa.z = f2bf(a.z); oa.w = f2bf(a.w);
    ob.x = f2bf(b.x); ob.y = f2bf(b.y); ob.z = f2bf(b.z); ob.w = f2bf(b.w);
    *(U16x4*)(H + e) = oa;
    *(U16x4*)(H + BD + e) = ob;
    float dot = a.x * b.x + a.y * b.y + a.z * b.z + a.w * b.w;
#pragma unroll
    for (int msk = 1; msk < 64; msk <<= 1) dot += __shfl_xor(dot, msk);
    int lane = threadIdx.x & 63, wid = threadIdx.x >> 6;
    if (lane == 0) red[wid] = dot;
    __syncthreads();
    if (threadIdx.x == 0) {
        Pos[blockIdx.x] = red[0] + red[1] + red[2] + red[3];
        if (blockIdx.x == 0) *out = 0.0f;
    }
}

// ------------- kernel 2: symmetric Gram, lower-triangle 256x256 tiles -------------
// 8-wave (2M x 4N) 256^2-tile, BK=64, double-buffered LDS (128 KiB), phase-split
// K-loop with counted vmcnt (T3+T4) + setprio (T5). LDS layout per K-tile buffer:
// [kh:2][row:256][chunk:4] 16B chunks; chunk swizzled by (chunk ^ (row&3)) applied
// on the SOURCE address (global_load_lds dest stays linear) and matched on ds_read.
// Staging unit = one K-half of A or B (16 KB, 2 loads/thread); each unit is issued
// 5-6 phases before first consumption so vmcnt(8) (4 units in flight) never drains
// the pipe.  Phase = {ds_read frags | stage 1 unit | vmcnt(8) | barrier | 16 MFMA |
// barrier}.  Epilogue: fused row/col max+sumexp partials as before (32 slots now).
#define LD8(buf, kk, off) (*(const short8*)&(buf)[(kk) * 8192 + (off)])
#define MFMA_(va, vb, c) __builtin_amdgcn_mfma_f32_16x16x32_bf16(va, vb, c, 0, 0, 0)

#define MF_ROW(mi, areg)                       \
    acc[mi][0] = MFMA_(areg, b0, acc[mi][0]);  \
    acc[mi][1] = MFMA_(areg, b1, acc[mi][1]);  \
    acc[mi][2] = MFMA_(areg, b2, acc[mi][2]);  \
    acc[mi][3] = MFMA_(areg, b3, acc[mi][3]);

#define STAGE2(srcp, dstp) {                   \
    async_copy16((srcp) + s0, (dstp) + d0);    \
    async_copy16((srcp) + s1, (dstp) + d1); }

#define PHASE(kk, mh, RB, STG)                                   \
    {                                                            \
        short8 a0 = LD8(cA, kk, offA[(mh)*4 + 0]);               \
        short8 a1 = LD8(cA, kk, offA[(mh)*4 + 1]);               \
        short8 a2 = LD8(cA, kk, offA[(mh)*4 + 2]);               \
        short8 a3 = LD8(cA, kk, offA[(mh)*4 + 3]);               \
        if (RB) {                                                \
            b0 = LD8(cB, kk, offB[0]);                           \
            b1 = LD8(cB, kk, offB[1]);                           \
            b2 = LD8(cB, kk, offB[2]);                           \
            b3 = LD8(cB, kk, offB[3]);                           \
        }                                                        \
        STG;                                                     \
        asm volatile("s_waitcnt vmcnt(8)" ::: "memory");         \
        __builtin_amdgcn_s_barrier();                            \
        asm volatile("" ::: "memory");                           \
        __builtin_amdgcn_s_setprio(1);                           \
        MF_ROW((mh)*4 + 0, a0)                                   \
        MF_ROW((mh)*4 + 1, a1)                                   \
        MF_ROW((mh)*4 + 2, a2)                                   \
        MF_ROW((mh)*4 + 3, a3)                                   \
        __builtin_amdgcn_s_setprio(0);                           \
        __builtin_amdgcn_s_barrier();                            \
        asm volatile("" ::: "memory");                           \
    }

__global__ __launch_bounds__(512, 2) void gram_kernel(const u16* __restrict__ H,
                                                      float* __restrict__ Mpart,
                                                      float* __restrict__ Spart) {
    __shared__ u16 As[2 * BUF];    // 64 KB
    __shared__ u16 Bs[2 * BUF];    // 64 KB

    const int tid  = threadIdx.x;
    const int lane = tid & 63;
    const int wid  = tid >> 6;        // 0..7
    const int quad = lane >> 4;
    const int ln15 = lane & 15;
    const int wr = wid >> 2;          // 0..1 : 128-row strip
    const int wc = wid & 3;           // 0..3 : 64-col strip

    // lower-triangle decode: blockIdx.x in [0, 528)
    int t = blockIdx.x;
    int bi = (int)((sqrtf(8.0f * (float)t + 1.0f) - 1.0f) * 0.5f);
    while ((bi + 1) * (bi + 2) / 2 <= t) bi++;
    while (bi * (bi + 1) / 2 > t) bi--;
    const int bj = t - bi * (bi + 1) / 2;
    const bool diag = (bi == bj);
    const int biBase = bi * 256, bjBase = bj * 256;

    const u16* __restrict__ HA = H + (size_t)biBase * DD;
    const u16* __restrict__ HB = H + (size_t)bjBase * DD;

    // staging addresses: unit = 256 rows x 32 K = 1024 chunks of 16B; thread stages
    // chunks c0 = tid, c1 = 512+tid.  src chunk k-pos = (c&3) ^ (row&3) (swizzle on
    // source side), dest = linear c*16B.
    const int c0 = tid,       r0 = c0 >> 2, p0 = c0 & 3;
    const int c1 = 512 + tid, r1 = c1 >> 2, p1 = c1 & 3;
    const int s0 = r0 * DD + ((p0 ^ (r0 & 3)) * 8), d0 = c0 * 8;
    const int s1 = r1 * DD + ((p1 ^ (r1 & 3)) * 8), d1 = c1 * 8;

    // fragment read offsets (element offset within a K-half of a buffer)
    int offA[8], offB[4];
#pragma unroll
    for (int m = 0; m < 8; m++) {
        int r = wr * 128 + m * 16 + ln15;
        offA[m] = (r * 4 + (quad ^ (r & 3))) * 8;
    }
#pragma unroll
    for (int n = 0; n < 4; n++) {
        int r = wc * 64 + n * 16 + ln15;
        offB[n] = (r * 4 + (quad ^ (r & 3))) * 8;
    }

    floatx4 acc[8][4];
#pragma unroll
    for (int i = 0; i < 8; i++)
#pragma unroll
        for (int j = 0; j < 4; j++) acc[i][j] = (floatx4)0.0f;

    // prologue: K-tile 0 complete (4 units) + K-tile 1 k0-halves (2 units)
    STAGE2(HA,      &As[0]);         // A-k0(0)
    STAGE2(HA + 32, &As[8192]);      // A-k1(0)
    STAGE2(HB,      &Bs[0]);         // B-k0(0)
    STAGE2(HB + 32, &Bs[8192]);      // B-k1(0)
    STAGE2(HA + 64, &As[BUF]);       // A-k0(1)
    STAGE2(HB + 64, &Bs[BUF]);       // B-k0(1)
    asm volatile("s_waitcnt vmcnt(4)" ::: "memory");
    __builtin_amdgcn_s_barrier();
    asm volatile("" ::: "memory");

    // main loop: 8 K-tiles of 64.  Steady staging per tile t:
    //  ph1: A-k1(t+1)  ph2: B-k1(t+1)  ph3: A-k0(t+2)  ph4: B-k0(t+2)
    // (regions free: k1(t+1) regions last read at ph3/4 of t-1; k0 regions of the
    //  current buffer last read at ph1/2 of t -> staged after the ph2 barrier.)
#pragma unroll 2
    for (int kt = 0; kt < 8; ++kt) {
        u16* cA = &As[(kt & 1) * BUF];
        u16* cB = &Bs[(kt & 1) * BUF];
        u16* nA = &As[((kt + 1) & 1) * BUF];
        u16* nB = &Bs[((kt + 1) & 1) * BUF];
        const int kn1 = (kt + 1) * 64, kn2 = (kt + 2) * 64;
        short8 b0, b1, b2, b3;
        PHASE(0, 0, 1, if (kt < 7) STAGE2(HA + kn1 + 32, nA + 8192))
        PHASE(0, 1, 0, if (kt < 7) STAGE2(HB + kn1 + 32, nB + 8192))
        PHASE(1, 0, 1, if (kt < 6) STAGE2(HA + kn2,      cA))
        PHASE(1, 1, 0, if (kt < 6) STAGE2(HB + kn2,      cB))
    }

    asm volatile("s_waitcnt vmcnt(0)" ::: "memory");
    __syncthreads();

    // scale in place; mask self-similarity on diagonal tiles
    // C/D layout: local row = wr*128 + m*16 + quad*4 + g, local col = wc*64 + n*16 + ln15
#pragma unroll
    for (int m = 0; m < 8; m++)
#pragma unroll
        for (int n = 0; n < 4; n++)
#pragma unroll
            for (int g = 0; g < 4; g++) {
                float v = SCALE * acc[m][n][g];
                if (diag) {
                    int lrow = wr * 128 + m * 16 + quad * 4 + g;
                    int lcol = wc * 64 + n * 16 + ln15;
                    if (lrow == lcol) v = -FLT_MAX;
                }
                acc[m][n][g] = v;
            }

    // epilogue scratch aliases onto As (K-loop done, all staging landed)
    float* Rm = (float*)&As[0];      // [4][256]
    float* Rs = Rm + 1024;           // [4][256]
    float* Cm = Rs + 1024;           // [2][256]
    float* Cs = Cm + 512;            // [2][256]

    // row pass: per-row max+sumexp over this wave's 64 cols
#pragma unroll
    for (int m = 0; m < 8; m++) {
#pragma unroll
        for (int g = 0; g < 4; g++) {
            float vmax = fmaxf(fmaxf(acc[m][0][g], acc[m][1][g]),
                               fmaxf(acc[m][2][g], acc[m][3][g]));
#pragma unroll
            for (int msk = 1; msk < 16; msk <<= 1)
                vmax = fmaxf(vmax, __shfl_xor(vmax, msk));
            float s = __expf(acc[m][0][g] - vmax) + __expf(acc[m][1][g] - vmax)
                    + __expf(acc[m][2][g] - vmax) + __expf(acc[m][3][g] - vmax);
#pragma unroll
            for (int msk = 1; msk < 16; msk <<= 1) s += __shfl_xor(s, msk);
            if (ln15 == 0) {
                int x = wr * 128 + m * 16 + quad * 4 + g;
                Rm[wc * 256 + x] = vmax; Rs[wc * 256 + x] = s;
            }
        }
    }

    // col pass (transpose tile): per-col max+sumexp over this wave's 128 rows
    if (!diag) {
#pragma unroll
        for (int n = 0; n < 4; n++) {
            float cm = -FLT_MAX;
#pragma unroll
            for (int m = 0; m < 8; m++)
#pragma unroll
                for (int g = 0; g < 4; g++) cm = fmaxf(cm, acc[m][n][g]);
            cm = fmaxf(cm, __shfl_xor(cm, 16));
            cm = fmaxf(cm, __shfl_xor(cm, 32));
            float s = 0.0f;
#pragma unroll
            for (int m = 0; m < 8; m++)
#pragma unroll
                for (int g = 0; g < 4; g++) s += __expf(acc[m][n][g] - cm);
            s += __shfl_xor(s, 16);
            s += __shfl_xor(s, 32);
            if (quad == 0) {
                int y = wc * 64 + n * 16 + ln15;
                Cm[wr * 256 + y] = cm; Cs[wr * 256 + y] = s;
            }
        }
    }
    __syncthreads();

    // merge wave strips, write slot-major partials: Mpart[slot*NN + globalRow]
    if (tid < 256) {
        float m0 = Rm[tid], m1 = Rm[256 + tid], m2 = Rm[512 + tid], m3 = Rm[768 + tid];
        float mm = fmaxf(fmaxf(m0, m1), fmaxf(m2, m3));
        float s = Rs[tid] * __expf(m0 - mm) + Rs[256 + tid] * __expf(m1 - mm)
                + Rs[512 + tid] * __expf(m2 - mm) + Rs[768 + tid] * __expf(m3 - mm);
        Mpart[(size_t)bj * NN + biBase + tid] = mm;
        Spart[(size_t)bj * NN + biBase + tid] = s;
    } else if (!diag) {
        int y = tid - 256;
        float m0 = Cm[y], m1 = Cm[256 + y];
        float mm = fmaxf(m0, m1);
        float s = Cs[y] * __expf(m0 - mm) + Cs[256 + y] * __expf(m1 - mm);
        Mpart[(size_t)bi * NN + bjBase + y] = mm;
        Spart[(size_t)bi * NN + bjBase + y] = s;
    }
}

// ------ kernel 3: combine 32 slot-partials per row + pos partials -> loss ------
// 128 blocks x 64 rows (4x parallelism vs old 32-block version); each wave covers
// 8 slots of its 64 rows, merged through LDS.
__global__ __launch_bounds__(256) void lse_kernel(const float* __restrict__ Mpart,
                                                  const float* __restrict__ Spart,
                                                  const float* __restrict__ Pos,
                                                  float* __restrict__ out) {
    __shared__ float sm[4][64], ss[4][64];
    __shared__ float red[256];
    int tid = threadIdx.x;
    int wid = tid >> 6, lane = tid & 63;
    int r = blockIdx.x * 64 + lane;
    float m = -FLT_MAX, s = 0.0f;
#pragma unroll
    for (int i = 0; i < 8; i++) {
        int c = wid * 8 + i;
        float mc = Mpart[(size_t)c * NN + r];   // coalesced: lane-stride 4B
        float sc = Spart[(size_t)c * NN + r];
        float mn = fmaxf(m, mc);
        s = s * __expf(m - mn) + sc * __expf(mc - mn);
        m = mn;
    }
    sm[wid][lane] = m; ss[wid][lane] = s;
    __syncthreads();
    float v = 0.0f;
    if (tid < 64) {
        float m0 = sm[0][tid], m1 = sm[1][tid], m2 = sm[2][tid], m3 = sm[3][tid];
        float mm = fmaxf(fmaxf(m0, m1), fmaxf(m2, m3));
        float sa = ss[0][tid] * __expf(m0 - mm) + ss[1][tid] * __expf(m1 - mm)
                 + ss[2][tid] * __expf(m2 - mm) + ss[3][tid] * __expf(m3 - mm);
        v = mm + logf(sa);
        if (tid < 16) v += -4.0f * Pos[blockIdx.x * 16 + tid];
    }
    red[tid] = v;
    __syncthreads();
    for (int st = 128; st > 0; st >>= 1) {
        if (tid < st) red[tid] += red[tid + st];
        __syncthreads();
    }
    if (tid == 0) atomicAdd(out, red[0] * (1.0f / (float)NN));
}

extern "C" void kernel_launch(void* const* d_in, const int* in_sizes, int n_in,
                              void* d_out, int out_size, void* d_ws, size_t ws_size,
                              hipStream_t stream) {
    const float* hi = (const float*)d_in[0];
    const float* hj = (const float*)d_in[1];
    float* out = (float*)d_out;

    u16*   H     = (u16*)d_ws;                                            // 8 MB
    float* Mpart = (float*)((char*)d_ws + (size_t)8 * 1024 * 1024);       // 1 MB used
    float* Spart = (float*)((char*)d_ws + (size_t)10 * 1024 * 1024);      // 1 MB used
    float* Pos   = (float*)((char*)d_ws + (size_t)12 * 1024 * 1024);      // 8 KB

    convert_pos_kernel<<<2048, 256, 0, stream>>>(hi, hj, H, Pos, out);

    gram_kernel<<<528, 512, 0, stream>>>(H, Mpart, Spart);   // 32*33/2 tiles

    lse_kernel<<<128, 256, 0, stream>>>(Mpart, Spart, Pos, out);
}

// Round 2
// 156.917 us; speedup vs baseline: 1.0105x; 1.0105x over previous
//
#include <hip/hip_runtime.h>
#include <hip/hip_bf16.h>
#include <float.h>

// B=4096, D=512, N=8192, temp=0.5
#define BN_ 4096
#define DD  512
#define NN  8192
#define SCALE 2.0f   // 1/temperature
#define BUF 16384    // elements per LDS K-tile buffer (256 rows x 64 K)

typedef unsigned short u16;
typedef __attribute__((ext_vector_type(8))) short short8;   // 8 bf16 = 4 VGPRs
typedef __attribute__((ext_vector_type(4))) float floatx4;  // MFMA acc

struct alignas(8) U16x4 { u16 x, y, z, w; };

__device__ __forceinline__ u16 f2bf(float f) {
    union { float f; unsigned u; } c; c.f = f;
    unsigned u = c.u;
    unsigned r = (u + 0x7fffu + ((u >> 16) & 1u)) >> 16;   // RNE
    return (u16)r;
}

__device__ __forceinline__ void async_copy16(const u16* g, u16* l) {
    __builtin_amdgcn_global_load_lds(
        (const __attribute__((address_space(1))) void*)g,
        (__attribute__((address_space(3))) void*)l, 16, 0, 0);
}

// ------ kernel 1: fp32 -> bf16 concat + per-block positive-dot partial ------
__global__ __launch_bounds__(256) void convert_pos_kernel(const float* __restrict__ hi,
                                                          const float* __restrict__ hj,
                                                          u16* __restrict__ H,
                                                          float* __restrict__ Pos,
                                                          float* __restrict__ out) {
    __shared__ float red[4];
    int t = blockIdx.x * 256 + threadIdx.x;     // 2048 blocks -> 524288 threads
    int e = t * 4;
    const int BD = BN_ * DD;
    float4 a = *(const float4*)(hi + e);
    float4 b = *(const float4*)(hj + e);
    U16x4 oa, ob;
    oa.x = f2bf(a.x); oa.y = f2bf(a.y); oa.z = f2bf(a.z); oa.w = f2bf(a.w);
    ob.x = f2bf(b.x); ob.y = f2bf(b.y); ob.z = f2bf(b.z); ob.w = f2bf(b.w);
    *(U16x4*)(H + e) = oa;
    *(U16x4*)(H + BD + e) = ob;
    float dot = a.x * b.x + a.y * b.y + a.z * b.z + a.w * b.w;
#pragma unroll
    for (int msk = 1; msk < 64; msk <<= 1) dot += __shfl_xor(dot, msk);
    int lane = threadIdx.x & 63, wid = threadIdx.x >> 6;
    if (lane == 0) red[wid] = dot;
    __syncthreads();
    if (threadIdx.x == 0) {
        Pos[blockIdx.x] = red[0] + red[1] + red[2] + red[3];
        if (blockIdx.x == 0) *out = 0.0f;
    }
}

// ------------- kernel 2: symmetric Gram, lower-triangle 256x256 tiles -------------
// 8-wave (2M x 4N), BK=64, double-buffered 128 KiB LDS, 4 phases per K-tile with
// counted vmcnt.  LDS layout per buffer: [row:256][chunk:8] 16B chunks, 128B rows
// (bank = chunk-pos only -> conflict-free), chunk swizzled ck^(row&7) on the
// SOURCE address (linear global_load_lds dest) and matched on ds_read.
// Staging unit = 128 rows (16KB, 2 loads/thread); 1 unit/phase, issue order
//   ... B1(t+1)@ph1, A0(t+1)@ph2, A1(t+1)@ph3, B0(t+2)@ph4 ...
// vmcnt at phase p protects the ds_reads of phase p+1 (after the barrier):
//   ph1: vmcnt(4)  ph2: vmcnt(8)  ph3: vmcnt(8)  ph4: vmcnt(4)   (never 0).
// Tail: k clamped to 448 -> redundant stages land in dead regions / write
// identical bytes; loop stays branch-free.
#define MFMA_(va, vb, c) __builtin_amdgcn_mfma_f32_16x16x32_bf16(va, vb, c, 0, 0, 0)

#define MF_ROW(mi, areg)                       \
    acc[mi][0] = MFMA_(areg, b0, acc[mi][0]);  \
    acc[mi][1] = MFMA_(areg, b1, acc[mi][1]);  \
    acc[mi][2] = MFMA_(areg, b2, acc[mi][2]);  \
    acc[mi][3] = MFMA_(areg, b3, acc[mi][3]);

#define VMWAIT(n) asm volatile("s_waitcnt vmcnt(" #n ")" ::: "memory")

#define STAGE(gb, k0, rbase, lb) {                                              \
    async_copy16((gb) + (size_t)(rbase) * DD + (k0) + so0, (lb) + (rbase) * 64 + do0); \
    async_copy16((gb) + (size_t)(rbase) * DD + (k0) + so1, (lb) + (rbase) * 64 + do1); }

#define PHASE(cA, cB, kkq, mh, RB, STG, VMn)                     \
    {                                                            \
        short8 a0 = *(const short8*)&cA[offA[kkq][(mh)*4 + 0]];  \
        short8 a1 = *(const short8*)&cA[offA[kkq][(mh)*4 + 1]];  \
        short8 a2 = *(const short8*)&cA[offA[kkq][(mh)*4 + 2]];  \
        short8 a3 = *(const short8*)&cA[offA[kkq][(mh)*4 + 3]];  \
        if (RB) {                                                \
            b0 = *(const short8*)&cB[offB[kkq][0]];              \
            b1 = *(const short8*)&cB[offB[kkq][1]];              \
            b2 = *(const short8*)&cB[offB[kkq][2]];              \
            b3 = *(const short8*)&cB[offB[kkq][3]];              \
        }                                                        \
        STG;                                                     \
        VMWAIT(VMn);                                             \
        __builtin_amdgcn_s_barrier();                            \
        asm volatile("" ::: "memory");                           \
        __builtin_amdgcn_s_setprio(1);                           \
        MF_ROW((mh)*4 + 0, a0)                                   \
        MF_ROW((mh)*4 + 1, a1)                                   \
        MF_ROW((mh)*4 + 2, a2)                                   \
        MF_ROW((mh)*4 + 3, a3)                                   \
        __builtin_amdgcn_s_setprio(0);                           \
        __builtin_amdgcn_s_barrier();                            \
        asm volatile("" ::: "memory");                           \
    }

__global__ __launch_bounds__(512, 2) void gram_kernel(const u16* __restrict__ H,
                                                      float* __restrict__ Mpart,
                                                      float* __restrict__ Spart) {
    __shared__ u16 As[2 * BUF];    // 64 KB
    __shared__ u16 Bs[2 * BUF];    // 64 KB

    const int tid  = threadIdx.x;
    const int lane = tid & 63;
    const int wid  = tid >> 6;        // 0..7
    const int quad = lane >> 4;
    const int ln15 = lane & 15;
    const int wr = wid >> 2;          // 0..1 : 128-row strip
    const int wc = wid & 3;           // 0..3 : 64-col strip

    // lower-triangle decode: blockIdx.x in [0, 528)
    int t = blockIdx.x;
    int bi = (int)((sqrtf(8.0f * (float)t + 1.0f) - 1.0f) * 0.5f);
    while ((bi + 1) * (bi + 2) / 2 <= t) bi++;
    while (bi * (bi + 1) / 2 > t) bi--;
    const int bj = t - bi * (bi + 1) / 2;
    const bool diag = (bi == bj);
    const int biBase = bi * 256, bjBase = bj * 256;

    const u16* __restrict__ HA = H + (size_t)biBase * DD;
    const u16* __restrict__ HB = H + (size_t)bjBase * DD;

    // staging per-thread offsets: chunk c = l*512+tid; row = c>>3, pos = c&7;
    // source k-slot = pos ^ (row&7) (row&7 == (c>>3)&7 since rbase % 128 == 0);
    // dest elem = rbase*64 + c*8 (linear in c -> wave-uniform base + lane*16B).
    const int c0 = tid, c1 = tid + 512;
    const size_t so0 = (size_t)(c0 >> 3) * DD + ((c0 & 7) ^ ((c0 >> 3) & 7)) * 8;
    const size_t so1 = (size_t)(c1 >> 3) * DD + ((c1 & 7) ^ ((c1 >> 3) & 7)) * 8;
    const int do0 = c0 * 8, do1 = c1 * 8;

    // fragment read offsets (elements within a buffer), conflict-free:
    // byte = (r*8 + ck')*16, bank group = ck'*4 only; 16 lanes span 8 groups.
    int offA[2][8], offB[2][4];
#pragma unroll
    for (int kk = 0; kk < 2; kk++) {
#pragma unroll
        for (int m = 0; m < 8; m++) {
            int r = wr * 128 + m * 16 + ln15;
            offA[kk][m] = (r * 8 + ((kk * 4 + quad) ^ (r & 7))) * 8;
        }
#pragma unroll
        for (int n = 0; n < 4; n++) {
            int r = wc * 64 + n * 16 + ln15;
            offB[kk][n] = (r * 8 + ((kk * 4 + quad) ^ (r & 7))) * 8;
        }
    }

    floatx4 acc[8][4];
#pragma unroll
    for (int i = 0; i < 8; i++)
#pragma unroll
        for (int j = 0; j < 4; j++) acc[i][j] = (floatx4)0.0f;

    // prologue: tile0 fully (B0,B1,A0,A1) + B0(1).  vmcnt(4) leaves A1(0),B0(1)
    // in flight; ph1 needs B0(0),B1(0),A0(0) landed.
    STAGE(HB, 0,  0,   &Bs[0]);
    STAGE(HB, 0,  128, &Bs[0]);
    STAGE(HA, 0,  0,   &As[0]);
    STAGE(HA, 0,  128, &As[0]);
    STAGE(HB, 64, 0,   &Bs[BUF]);
    VMWAIT(4);
    __builtin_amdgcn_s_barrier();
    asm volatile("" ::: "memory");

    // main loop: 8 K-tiles of 64, phases (kk, M-half):
    //   ph1 (0,0): reads A[0-127]+B all | ph2 (0,1): A[128-255]
    //   ph3 (1,0): A[0-127]+B all       | ph4 (1,1): A[128-255]
#pragma unroll 2
    for (int kt = 0; kt < 8; ++kt) {
        u16* cA = &As[(kt & 1) * BUF];
        u16* cB = &Bs[(kt & 1) * BUF];
        u16* nA = &As[((kt + 1) & 1) * BUF];
        u16* nB = &Bs[((kt + 1) & 1) * BUF];
        int k1 = (kt + 1) * 64; if (k1 > 448) k1 = 448;
        int k2 = (kt + 2) * 64; if (k2 > 448) k2 = 448;
        short8 b0, b1, b2, b3;
        PHASE(cA, cB, 0, 0, 1, STAGE(HB, k1, 128, nB), 4)
        PHASE(cA, cB, 0, 1, 0, STAGE(HA, k1, 0,   nA), 8)
        PHASE(cA, cB, 1, 0, 1, STAGE(HA, k1, 128, nA), 8)
        PHASE(cA, cB, 1, 1, 0, STAGE(HB, k2, 0,   cB), 4)
    }

    asm volatile("s_waitcnt vmcnt(0)" ::: "memory");
    __syncthreads();

    // scale in place; mask self-similarity on diagonal tiles
    // C/D layout: local row = wr*128 + m*16 + quad*4 + g, local col = wc*64 + n*16 + ln15
#pragma unroll
    for (int m = 0; m < 8; m++)
#pragma unroll
        for (int n = 0; n < 4; n++)
#pragma unroll
            for (int g = 0; g < 4; g++) {
                float v = SCALE * acc[m][n][g];
                if (diag) {
                    int lrow = wr * 128 + m * 16 + quad * 4 + g;
                    int lcol = wc * 64 + n * 16 + ln15;
                    if (lrow == lcol) v = -FLT_MAX;
                }
                acc[m][n][g] = v;
            }

    // epilogue scratch aliases onto As (all staging drained above)
    float* Rm = (float*)&As[0];      // [4][256]
    float* Rs = Rm + 1024;           // [4][256]
    float* Cm = Rs + 1024;           // [2][256]
    float* Cs = Cm + 512;            // [2][256]

    // row pass: per-row max+sumexp over this wave's 64 cols
#pragma unroll
    for (int m = 0; m < 8; m++) {
#pragma unroll
        for (int g = 0; g < 4; g++) {
            float vmax = fmaxf(fmaxf(acc[m][0][g], acc[m][1][g]),
                               fmaxf(acc[m][2][g], acc[m][3][g]));
#pragma unroll
            for (int msk = 1; msk < 16; msk <<= 1)
                vmax = fmaxf(vmax, __shfl_xor(vmax, msk));
            float s = __expf(acc[m][0][g] - vmax) + __expf(acc[m][1][g] - vmax)
                    + __expf(acc[m][2][g] - vmax) + __expf(acc[m][3][g] - vmax);
#pragma unroll
            for (int msk = 1; msk < 16; msk <<= 1) s += __shfl_xor(s, msk);
            if (ln15 == 0) {
                int x = wr * 128 + m * 16 + quad * 4 + g;
                Rm[wc * 256 + x] = vmax; Rs[wc * 256 + x] = s;
            }
        }
    }

    // col pass (transpose tile): per-col max+sumexp over this wave's 128 rows
    if (!diag) {
#pragma unroll
        for (int n = 0; n < 4; n++) {
            float cm = -FLT_MAX;
#pragma unroll
            for (int m = 0; m < 8; m++)
#pragma unroll
                for (int g = 0; g < 4; g++) cm = fmaxf(cm, acc[m][n][g]);
            cm = fmaxf(cm, __shfl_xor(cm, 16));
            cm = fmaxf(cm, __shfl_xor(cm, 32));
            float s = 0.0f;
#pragma unroll
            for (int m = 0; m < 8; m++)
#pragma unroll
                for (int g = 0; g < 4; g++) s += __expf(acc[m][n][g] - cm);
            s += __shfl_xor(s, 16);
            s += __shfl_xor(s, 32);
            if (quad == 0) {
                int y = wc * 64 + n * 16 + ln15;
                Cm[wr * 256 + y] = cm; Cs[wr * 256 + y] = s;
            }
        }
    }
    __syncthreads();

    // merge wave strips, write slot-major partials: Mpart[slot*NN + globalRow]
    if (tid < 256) {
        float m0 = Rm[tid], m1 = Rm[256 + tid], m2 = Rm[512 + tid], m3 = Rm[768 + tid];
        float mm = fmaxf(fmaxf(m0, m1), fmaxf(m2, m3));
        float s = Rs[tid] * __expf(m0 - mm) + Rs[256 + tid] * __expf(m1 - mm)
                + Rs[512 + tid] * __expf(m2 - mm) + Rs[768 + tid] * __expf(m3 - mm);
        Mpart[(size_t)bj * NN + biBase + tid] = mm;
        Spart[(size_t)bj * NN + biBase + tid] = s;
    } else if (!diag) {
        int y = tid - 256;
        float m0 = Cm[y], m1 = Cm[256 + y];
        float mm = fmaxf(m0, m1);
        float s = Cs[y] * __expf(m0 - mm) + Cs[256 + y] * __expf(m1 - mm);
        Mpart[(size_t)bi * NN + bjBase + y] = mm;
        Spart[(size_t)bi * NN + bjBase + y] = s;
    }
}

// ------ kernel 3: combine 32 slot-partials per row + pos partials -> loss ------
__global__ __launch_bounds__(256) void lse_kernel(const float* __restrict__ Mpart,
                                                  const float* __restrict__ Spart,
                                                  const float* __restrict__ Pos,
                                                  float* __restrict__ out) {
    __shared__ float sm[4][64], ss[4][64];
    __shared__ float red[256];
    int tid = threadIdx.x;
    int wid = tid >> 6, lane = tid & 63;
    int r = blockIdx.x * 64 + lane;
    float m = -FLT_MAX, s = 0.0f;
#pragma unroll
    for (int i = 0; i < 8; i++) {
        int c = wid * 8 + i;
        float mc = Mpart[(size_t)c * NN + r];   // coalesced: lane-stride 4B
        float sc = Spart[(size_t)c * NN + r];
        float mn = fmaxf(m, mc);
        s = s * __expf(m - mn) + sc * __expf(mc - mn);
        m = mn;
    }
    sm[wid][lane] = m; ss[wid][lane] = s;
    __syncthreads();
    float v = 0.0f;
    if (tid < 64) {
        float m0 = sm[0][tid], m1 = sm[1][tid], m2 = sm[2][tid], m3 = sm[3][tid];
        float mm = fmaxf(fmaxf(m0, m1), fmaxf(m2, m3));
        float sa = ss[0][tid] * __expf(m0 - mm) + ss[1][tid] * __expf(m1 - mm)
                 + ss[2][tid] * __expf(m2 - mm) + ss[3][tid] * __expf(m3 - mm);
        v = mm + logf(sa);
        if (tid < 16) v += -4.0f * Pos[blockIdx.x * 16 + tid];
    }
    red[tid] = v;
    __syncthreads();
    for (int st = 128; st > 0; st >>= 1) {
        if (tid < st) red[tid] += red[tid + st];
        __syncthreads();
    }
    if (tid == 0) atomicAdd(out, red[0] * (1.0f / (float)NN));
}

extern "C" void kernel_launch(void* const* d_in, const int* in_sizes, int n_in,
                              void* d_out, int out_size, void* d_ws, size_t ws_size,
                              hipStream_t stream) {
    const float* hi = (const float*)d_in[0];
    const float* hj = (const float*)d_in[1];
    float* out = (float*)d_out;

    u16*   H     = (u16*)d_ws;                                            // 8 MB
    float* Mpart = (float*)((char*)d_ws + (size_t)8 * 1024 * 1024);       // 1 MB used
    float* Spart = (float*)((char*)d_ws + (size_t)10 * 1024 * 1024);      // 1 MB used
    float* Pos   = (float*)((char*)d_ws + (size_t)12 * 1024 * 1024);      // 8 KB

    convert_pos_kernel<<<2048, 256, 0, stream>>>(hi, hj, H, Pos, out);

    gram_kernel<<<528, 512, 0, stream>>>(H, Mpart, Spart);   // 32*33/2 tiles

    lse_kernel<<<128, 256, 0, stream>>>(Mpart, Spart, Pos, out);
}